// Round 3
// baseline (56.571 us; speedup 1.0000x reference)
//
#include <hip/hip_runtime.h>
#include <math.h>

#define DIM 4096
#define NRF 8192
#define NBLK 1024
#define TPB  512
#define NV4  (DIM / 4)        // 1024 float4 per row
#define ROWS_PER_BLOCK 8      // 8 waves/block, 1 row-pair per wave

typedef float f32x4 __attribute__((ext_vector_type(4)));

// ---------- Fused kernel ----------
// grid = 1024 x 512 (8 waves). Wave w of block b owns rf row = b*8+w:
// dot(gs_x[row], x) + dot(gs_w[row], w), x/w staged in LDS, sumsq fused.
// gs_w is loaded NON-TEMPORAL (streams from HBM, no L3 allocation) so the
// 134 MB gs_x stays L3-resident across graph replays instead of thrashing.
// Block partial sums are atomicAdd'ed (f32) into d_out[0] (memset to 0 first).
__global__ __launch_bounds__(TPB, 8) void k_main(const f32x4* __restrict__ gsx,
                                                 const f32x4* __restrict__ gsw,
                                                 const float* __restrict__ xis,
                                                 const f32x4* __restrict__ x4,
                                                 const f32x4* __restrict__ w4,
                                                 float* __restrict__ out) {
    __shared__ f32x4 lx[NV4];
    __shared__ f32x4 lw[NV4];
    __shared__ float ssq_s[8];
    __shared__ float wsum[8];

    int t = threadIdx.x;
    int lane = t & 63;
    int wid  = t >> 6;

    // Stage x, w into LDS (each thread moves 2 vec4 of each).
    f32x4 a0 = x4[t], a1 = x4[t + TPB];
    f32x4 b0 = w4[t], b1 = w4[t + TPB];
    lx[t] = a0; lx[t + TPB] = a1;
    lw[t] = b0; lw[t + TPB] = b1;

    // Fused ||x||^2 + ||w||^2 from staged registers.
    float ssq = a0.x*a0.x + a0.y*a0.y + a0.z*a0.z + a0.w*a0.w
              + a1.x*a1.x + a1.y*a1.y + a1.z*a1.z + a1.w*a1.w
              + b0.x*b0.x + b0.y*b0.y + b0.z*b0.z + b0.w*b0.w
              + b1.x*b1.x + b1.y*b1.y + b1.z*b1.z + b1.w*b1.w;
    #pragma unroll
    for (int off = 32; off >= 1; off >>= 1) ssq += __shfl_xor(ssq, off);
    if (lane == 0) ssq_s[wid] = ssq;
    __syncthreads();
    float sxw = ssq_s[0] + ssq_s[1] + ssq_s[2] + ssq_s[3]
              + ssq_s[4] + ssq_s[5] + ssq_s[6] + ssq_s[7];

    int row = blockIdx.x * ROWS_PER_BLOCK + wid;
    const f32x4* __restrict__ rx = gsx + (size_t)row * NV4;
    const f32x4* __restrict__ rw = gsw + (size_t)row * NV4;

    float dx0 = 0.f, dx1 = 0.f, dw0 = 0.f, dw1 = 0.f;
    #pragma unroll
    for (int k = 0; k < NV4 / 64; k += 2) {        // 8 unrolled iters
        f32x4 a = rx[k * 64 + lane];                           // L3-cached leg
        f32x4 b = lx[k * 64 + lane];
        dx0 += a.x*b.x + a.y*b.y + a.z*b.z + a.w*b.w;
        f32x4 c = rx[(k + 1) * 64 + lane];
        f32x4 d = lx[(k + 1) * 64 + lane];
        dx1 += c.x*d.x + c.y*d.y + c.z*d.z + c.w*d.w;
        f32x4 e = __builtin_nontemporal_load(&rw[k * 64 + lane]);      // HBM stream leg
        f32x4 f = lw[k * 64 + lane];
        dw0 += e.x*f.x + e.y*f.y + e.z*f.z + e.w*f.w;
        f32x4 g = __builtin_nontemporal_load(&rw[(k + 1) * 64 + lane]);
        f32x4 h = lw[(k + 1) * 64 + lane];
        dw1 += g.x*h.x + g.y*h.y + g.z*h.z + g.w*h.w;
    }
    float s = (dx0 + dx1) + (dw0 + dw1);
    #pragma unroll
    for (int off = 32; off >= 1; off >>= 1) s += __shfl_xor(s, off);

    if (lane == 0) {
        float xi = xis[row];
        float e  = xi * s - 0.5f * xi * xi * sxw;
        wsum[wid] = expf(e);
    }
    __syncthreads();
    if (t == 0) {
        float bsum = (wsum[0] + wsum[1] + wsum[2] + wsum[3]
                    + wsum[4] + wsum[5] + wsum[6] + wsum[7]) * (1.0f / (float)NRF);
        atomicAdd(out, bsum);
    }
}

extern "C" void kernel_launch(void* const* d_in, const int* in_sizes, int n_in,
                              void* d_out, int out_size, void* d_ws, size_t ws_size,
                              hipStream_t stream) {
    const float* x    = (const float*)d_in[0];   // [4096]
    const float* w    = (const float*)d_in[1];   // [4096]
    const float* xis  = (const float*)d_in[2];   // [8192]
    const f32x4* gsx  = (const f32x4*)d_in[3];   // [8192,4096]
    const f32x4* gsw  = (const f32x4*)d_in[4];   // [8192,4096]
    float* out = (float*)d_out;

    hipMemsetAsync(out, 0, sizeof(float), stream);
    k_main<<<NBLK, TPB, 0, stream>>>(gsx, gsw, xis,
                                     (const f32x4*)x, (const f32x4*)w, out);
}